// Round 9
// baseline (60.744 us; speedup 1.0000x reference)
//
#include <hip/hip_runtime.h>
#include <hip/hip_bf16.h>

#define N_NODES 4096
#define IN_DIMC 512
#define NHEADS 4
#define DHEAD 64
#define OUT_COLS 256  // NHEADS*DHEAD
#define HPB (N_NODES * DHEAD * 2)  // 512 KB per head

typedef __attribute__((ext_vector_type(8))) short short8;
typedef __attribute__((ext_vector_type(4))) float f32x4;

__device__ __forceinline__ short bf16b(float x) {
    return __builtin_bit_cast(short, __float2bfloat16(x));
}
__device__ __forceinline__ void gload16(const void* g, void* l) {
    __builtin_amdgcn_global_load_lds((const __attribute__((address_space(1))) void*)g,
                                     (__attribute__((address_space(3))) void*)l,
                                     16, 0, 0);
}
__device__ __forceinline__ void gload4(const void* g, void* l) {
    __builtin_amdgcn_global_load_lds((const __attribute__((address_space(1))) void*)g,
                                     (__attribute__((address_space(3))) void*)l,
                                     4, 0, 0);
}

// ---- Kernel A: fused {h-GEMM + hP/exp-table epilogue} and {adjacency bitpack} ----
// grid 1536: blocks [0,512) gemm (128 m-tiles x 4 heads); [512,1536) pack.
__global__ __launch_bounds__(256) void k_prep2(
    const float* __restrict__ A, const float* __restrict__ W,
    const float* __restrict__ att, const int* __restrict__ adj,
    char* __restrict__ hP, float* __restrict__ E1, float* __restrict__ F1,
    float* __restrict__ E2, float* __restrict__ F2,
    unsigned* __restrict__ bits32)
{
    const int t = (int)threadIdx.x;
    if (blockIdx.x >= 512) {
        // ---- pack: row i per wave; u32 word per 32-j chunk: bits32[j/32][i] ----
        const int pb = (int)blockIdx.x - 512;
        const int i = pb * 4 + (t >> 6);       // 0..4095
        const int lane = t & 63;
        const int* arow = adj + (size_t)i * N_NODES;
        #pragma unroll 2
        for (int it = 0; it < 16; ++it) {
            const int c = it * 4;
            const int a0 = arow[(c + 0) * 64 + lane];
            const int a1 = arow[(c + 1) * 64 + lane];
            const int a2 = arow[(c + 2) * 64 + lane];
            const int a3 = arow[(c + 3) * 64 + lane];
            const unsigned long long m0 = __ballot(a0 != 0);
            const unsigned long long m1 = __ballot(a1 != 0);
            const unsigned long long m2 = __ballot(a2 != 0);
            const unsigned long long m3 = __ballot(a3 != 0);
            if (lane == 0) {
                bits32[(size_t)(2 * c + 0) * N_NODES + i] = (unsigned)m0;
                bits32[(size_t)(2 * c + 1) * N_NODES + i] = (unsigned)(m0 >> 32);
                bits32[(size_t)(2 * c + 2) * N_NODES + i] = (unsigned)m1;
                bits32[(size_t)(2 * c + 3) * N_NODES + i] = (unsigned)(m1 >> 32);
                bits32[(size_t)(2 * c + 4) * N_NODES + i] = (unsigned)m2;
                bits32[(size_t)(2 * c + 5) * N_NODES + i] = (unsigned)(m2 >> 32);
                bits32[(size_t)(2 * c + 6) * N_NODES + i] = (unsigned)m3;
                bits32[(size_t)(2 * c + 7) * N_NODES + i] = (unsigned)(m3 >> 32);
            }
        }
        return;
    }
    // ---- gemm: tile 32(nodes) x 64(d) = one head slice ----
    __shared__ float As[32][36];
    __shared__ float Bs[32][68];
    __shared__ float ht[64][33];
    const int m0 = ((int)blockIdx.x & 127) * 32;
    const int head = (int)blockIdx.x >> 7;
    const int n0 = head * 64;
    const int tm = t & 7, tn = t >> 3;
    float acc[4][2] = {};
    for (int k0 = 0; k0 < IN_DIMC; k0 += 32) {
        {
            const int r = t >> 3, kc = (t & 7) << 2;
            float4 v0 = *(const float4*)(A + (size_t)(m0 + r) * IN_DIMC + k0 + kc);
            As[kc + 0][r] = v0.x; As[kc + 1][r] = v0.y; As[kc + 2][r] = v0.z; As[kc + 3][r] = v0.w;
            const int rb = t >> 4, nc = (t & 15) << 2;
            float4 w0 = *(const float4*)(W + (size_t)(k0 + rb) * OUT_COLS + n0 + nc);
            float4 w1 = *(const float4*)(W + (size_t)(k0 + rb + 16) * OUT_COLS + n0 + nc);
            *(float4*)&Bs[rb][nc] = w0;
            *(float4*)&Bs[rb + 16][nc] = w1;
        }
        __syncthreads();
        #pragma unroll
        for (int kk = 0; kk < 32; ++kk) {
            const f32x4 a = *(const f32x4*)&As[kk][tm << 2];
            const float b0 = Bs[kk][tn * 2], b1 = Bs[kk][tn * 2 + 1];
            #pragma unroll
            for (int i = 0; i < 4; ++i) {
                acc[i][0] = fmaf(a[i], b0, acc[i][0]);
                acc[i][1] = fmaf(a[i], b1, acc[i][1]);
            }
        }
        __syncthreads();
    }
    #pragma unroll
    for (int i = 0; i < 4; ++i) {
        ht[tn * 2 + 0][(tm << 2) + i] = acc[i][0];
        ht[tn * 2 + 1][(tm << 2) + i] = acc[i][1];
    }
    __syncthreads();
    {   // packed hP: (d,j) -> 16B-slot ((g*4 + d/16)*64 + qq*16 + d%16), g=j/32
        const int d = t >> 2, qq = t & 3;
        short8 hv;
        #pragma unroll
        for (int k = 0; k < 8; ++k) hv[k] = bf16b(ht[d][qq * 8 + k]);
        const size_t off16 = ((size_t)(m0 >> 5) * 4 + (d >> 4)) * 64 + qq * 16 + (d & 15);
        *(short8*)(hP + (size_t)head * HPB + off16 * 16) = hv;
    }
    {   // s1/s2 -> exp tables
        const int r = t >> 3, part = t & 7;
        float p1 = 0.f, p2 = 0.f;
        #pragma unroll
        for (int dd = 0; dd < 8; ++dd) {
            const int d = part * 8 + dd;
            const float v = ht[d][r];
            p1 = fmaf(v, att[head * 128 + d], p1);
            p2 = fmaf(v, att[head * 128 + 64 + d], p2);
        }
        p1 += __shfl_xor(p1, 1); p1 += __shfl_xor(p1, 2); p1 += __shfl_xor(p1, 4);
        p2 += __shfl_xor(p2, 1); p2 += __shfl_xor(p2, 2); p2 += __shfl_xor(p2, 4);
        if (part == 0) {
            const int idx = head * N_NODES + m0 + r;
            E1[idx] = __expf(p1);
            F1[idx] = __expf(0.2f * p1);
            E2[idx] = __expf(p2);
            F2[idx] = __expf(0.2f * p2);
        }
    }
}

// ---- Kernel C: 32-i waves, 32-j steps, pure-gload_lds vmcnt pipeline ----
// grid (128, 4): i-tile 32, j-quarter per block. Block 512 = 8 waves =
// 4 heads x 2 jsegs (512 j each = 16 steps of 32 j).
// Per wave: private 2 x 4608B buf: [hP 4KB][E2 128][F2 128][bits 128][pad].
// 73.7 KB LDS -> 2 blocks/CU -> 4 waves/SIMD.
__global__ __launch_bounds__(512, 4) void k_gat(
    const unsigned* __restrict__ bits32, const char* __restrict__ hP,
    const float* __restrict__ E1, const float* __restrict__ F1,
    const float* __restrict__ E2, const float* __restrict__ F2,
    float* __restrict__ pA, float* __restrict__ pB,
    float* __restrict__ pC, float* __restrict__ pD, float* __restrict__ pDen)
{
    __shared__ __align__(16) char stage[8 * 9216];   // 72 KB
    const int i0 = (int)blockIdx.x * 32;
    const int by = (int)blockIdx.y;                  // j-quarter
    const int t = (int)threadIdx.x;
    const int w = t >> 6, lane = t & 63, il = lane & 15, q = lane >> 4;
    const int head = w & 3, jseg = w >> 2;
    const int jbase = by * 1024 + jseg * 512;        // 16 steps of 32 j
    char* myst = stage + w * 9216;
    const char* hPh = hP + (size_t)head * HPB;
    const float* E2h = E2 + head * N_NODES;
    const float* F2h = F2 + head * N_NODES;
    const float e1a = E1[head * N_NODES + i0 + il];
    const float e1b = E1[head * N_NODES + i0 + 16 + il];
    const float f1a = F1[head * N_NODES + i0 + il];
    const float f1b = F1[head * N_NODES + i0 + 16 + il];
    f32x4 acc[4][2] = {};
    f32x4 accD[2] = {};
    short8 ones;
    #pragma unroll
    for (int e = 0; e < 8; ++e) ones[e] = (short)0x3F80;

    const int g0 = jbase >> 5;      // 32-j tile index base (= bits32 chunk index)
    // one batch = 7 gloads: 4x hP(1KB) + E2 + F2 + bits (half-wave gload4)
    auto issue = [&](int bs, char* dst) {
        const char* hsrc = hPh + (size_t)(g0 + bs) * 4096;
        #pragma unroll
        for (int k = 0; k < 4; ++k)
            gload16(hsrc + k * 1024 + lane * 16, dst + k * 1024);
        if (lane < 32) {
            gload4(E2h + jbase + bs * 32 + lane, dst + 4096);
            gload4(F2h + jbase + bs * 32 + lane, dst + 4224);
            gload4((const char*)(bits32 + (size_t)(g0 + bs) * N_NODES + i0) + lane * 4,
                   dst + 4352);
        }
    };
    issue(0, myst);
    #pragma unroll 2
    for (int s = 0; s < 16; ++s) {
        if (s < 15) {
            issue(s + 1, myst + ((s + 1) & 1) * 4608);
            asm volatile("s_waitcnt vmcnt(7)" ::: "memory");  // batch s landed
        } else {
            asm volatile("s_waitcnt vmcnt(0)" ::: "memory");  // drain (no race w/ epilogue)
        }
        const char* base = myst + (s & 1) * 4608;
        const unsigned uA = *(const unsigned*)(base + 4352 + il * 4);
        const unsigned uB = *(const unsigned*)(base + 4352 + 64 + il * 4);
        const f32x4 ea = *(const f32x4*)(base + 4096 + q * 32);
        const f32x4 eb = *(const f32x4*)(base + 4096 + q * 32 + 16);
        const f32x4 fa = *(const f32x4*)(base + 4224 + q * 32);
        const f32x4 fb2 = *(const f32x4*)(base + 4224 + q * 32 + 16);
        const unsigned mA = (uA >> (q * 8)) & 0xffu;
        const unsigned mB = (uB >> (q * 8)) & 0xffu;
        short8 afA, afB;
        #pragma unroll
        for (int e = 0; e < 8; ++e) {
            const float Ev = (e < 4) ? ea[e] : eb[e - 4];
            const float Fv = (e < 4) ? fa[e] : fb2[e - 4];
            const float pa = fmaxf(e1a * Ev, f1a * Fv);
            const float pb = fmaxf(e1b * Ev, f1b * Fv);
            afA[e] = bf16b(((mA >> e) & 1u) ? pa : 0.f);
            afB[e] = bf16b(((mB >> e) & 1u) ? pb : 0.f);
        }
        #pragma unroll
        for (int dblk = 0; dblk < 4; ++dblk) {
            const short8 bfrag = *(const short8*)(base + dblk * 1024 + lane * 16);
            acc[dblk][0] = __builtin_amdgcn_mfma_f32_16x16x32_bf16(afA, bfrag, acc[dblk][0], 0, 0, 0);
            acc[dblk][1] = __builtin_amdgcn_mfma_f32_16x16x32_bf16(afB, bfrag, acc[dblk][1], 0, 0, 0);
        }
        accD[0] = __builtin_amdgcn_mfma_f32_16x16x32_bf16(afA, ones, accD[0], 0, 0, 0);
        accD[1] = __builtin_amdgcn_mfma_f32_16x16x32_bf16(afB, ones, accD[1], 0, 0, 0);
    }
    // ---- epilogue: jseg-pair reduction in LDS, write partials for quarter 'by' ----
    __syncthreads();
    float* ep = (float*)stage;           // 4 waves x 2560 f32 = 40 KB
    if (jseg == 1) {
        float* dst = ep + (w - 4) * 2560;
        #pragma unroll
        for (int dblk = 0; dblk < 4; ++dblk)
            #pragma unroll
            for (int sub = 0; sub < 2; ++sub)
                #pragma unroll
                for (int r = 0; r < 4; ++r)
                    dst[(dblk * 8 + sub * 4 + r) * 64 + lane] = acc[dblk][sub][r];
        #pragma unroll
        for (int sub = 0; sub < 2; ++sub)
            #pragma unroll
            for (int r = 0; r < 4; ++r)
                dst[(32 + sub * 4 + r) * 64 + lane] = accD[sub][r];
    }
    __syncthreads();
    if (jseg == 0) {
        const float* src = ep + w * 2560;
        float* po = (by == 0) ? pA : (by == 1) ? pB : (by == 2) ? pC : pD;
        #pragma unroll
        for (int sub = 0; sub < 2; ++sub) {
            #pragma unroll
            for (int r = 0; r < 4; ++r) {
                const int row = i0 + sub * 16 + q * 4 + r;   // C/D: row=(lane>>4)*4+reg
                #pragma unroll
                for (int dblk = 0; dblk < 4; ++dblk) {
                    const float v = acc[dblk][sub][r] + src[(dblk * 8 + sub * 4 + r) * 64 + lane];
                    po[(size_t)row * OUT_COLS + head * DHEAD + dblk * 16 + il] = v;
                }
                if (il == 0) {
                    const float d = accD[sub][r] + src[(32 + sub * 4 + r) * 64 + lane];
                    pDen[by * (NHEADS * N_NODES) + head * N_NODES + row] = d;
                }
            }
        }
    }
}

// ---- Kernel F: combine 4 j-quarter partials, divide, bias ----
__global__ __launch_bounds__(256) void k_fin(
    const float* __restrict__ pB, const float* __restrict__ pC,
    const float* __restrict__ pD, const float* __restrict__ pDen,
    const float* __restrict__ bias, float* __restrict__ outp)
{
    const int gid = (int)blockIdx.x * 256 + (int)threadIdx.x;  // 262144
    const int i = gid >> 6;
    const int c4 = (gid & 63) << 2;
    const int head = c4 >> 6;
    const float4 v0 = *(const float4*)(outp + (size_t)i * OUT_COLS + c4);
    const float4 v1 = *(const float4*)(pB + (size_t)i * OUT_COLS + c4);
    const float4 v2 = *(const float4*)(pC + (size_t)i * OUT_COLS + c4);
    const float4 v3 = *(const float4*)(pD + (size_t)i * OUT_COLS + c4);
    const float d = pDen[head * N_NODES + i]
                  + pDen[1 * NHEADS * N_NODES + head * N_NODES + i]
                  + pDen[2 * NHEADS * N_NODES + head * N_NODES + i]
                  + pDen[3 * NHEADS * N_NODES + head * N_NODES + i];
    const float inv = 1.0f / d;
    const float4 bb = *(const float4*)(bias + c4);
    float4 r;
    r.x = (v0.x + v1.x + v2.x + v3.x) * inv + bb.x;
    r.y = (v0.y + v1.y + v2.y + v3.y) * inv + bb.y;
    r.z = (v0.z + v1.z + v2.z + v3.z) * inv + bb.z;
    r.w = (v0.w + v1.w + v2.w + v3.w) * inv + bb.w;
    *(float4*)(outp + (size_t)i * OUT_COLS + c4) = r;
}

extern "C" void kernel_launch(void* const* d_in, const int* in_sizes, int n_in,
                              void* d_out, int out_size, void* d_ws, size_t ws_size,
                              hipStream_t stream) {
    const float* features  = (const float*)d_in[0];
    const int*   adjacency = (const int*)d_in[1];
    const float* weights   = (const float*)d_in[2];
    const float* attention = (const float*)d_in[3];
    const float* bias      = (const float*)d_in[4];
    float* out = (float*)d_out;

    char* ws = (char*)d_ws;
    char*     hP     = ws;                                          // 2 MB
    float*    E1     = (float*)(ws + 2u*1024*1024);                 // 64 KB
    float*    F1     = (float*)(ws + 2u*1024*1024 +  64u*1024);
    float*    E2     = (float*)(ws + 2u*1024*1024 + 128u*1024);
    float*    F2     = (float*)(ws + 2u*1024*1024 + 192u*1024);
    unsigned* bits32 = (unsigned*)(ws + 2u*1024*1024 + 256u*1024);  // 2 MB
    float*    pB     = (float*)(ws + 4u*1024*1024 + 256u*1024);     // 4 MB
    float*    pC     = (float*)(ws + 8u*1024*1024 + 256u*1024);     // 4 MB
    float*    pD     = (float*)(ws + 12u*1024*1024 + 256u*1024);    // 4 MB
    float*    pDen   = (float*)(ws + 16u*1024*1024 + 256u*1024);    // 256 KB

    k_prep2<<<dim3(1536), 256, 0, stream>>>(features, weights, attention, adjacency,
                                            hP, E1, F1, E2, F2, bits32);
    k_gat<<<dim3(128, 4), 512, 0, stream>>>(bits32, hP, E1, F1, E2, F2,
                                            out /*pA*/, pB, pC, pD, pDen);
    k_fin<<<dim3(1024), 256, 0, stream>>>(pB, pC, pD, pDen, bias, out);
}